// Round 8
// baseline (281.500 us; speedup 1.0000x reference)
//
#include <hip/hip_runtime.h>

// geodesic loss: mean(acos(clip((sum(ypred*ytrue per 3x3) - 1)*0.5, -1+eps, 1-eps)))
// B = 4,194,304 samples x 9 f32 per input; 302 MB read, ~0 written.
//
// History: R1/R2/R3(LDS dbuf+counted vmcnt) all ~112 us (2.7 TB/s). R5 added
// NT (non-temporal) cache policy -> geo_partial ~79 us (3.8 TB/s): the win was
// cache-policy (no L2/L3 alloc vs harness's 302 MB restore churn), not MLP.
// R7 (=R6 with compile fix: clang ext_vector type for the NT builtin):
// drop LDS/barriers entirely. Fully-coalesced NT register loads (lane l ->
// float4 it*63+l), 9-float sample boundaries resolved in-register via 2
// shuffles (lcm(4,9)=36: 9 lanes = 4 samples, 63 lanes = 28 samples/wave-iter),
// 4-deep unroll = 8 independent NT dwordx4 in flight per wave body, no LDS ->
// full occupancy.

typedef float f32x4 __attribute__((ext_vector_type(4)));

constexpr int TPB  = 256;
constexpr int NBLK = 2048;
constexpr float EPSF = 1e-6f;

__device__ __forceinline__ double block_reduce(double v) {
    __shared__ double sm[TPB / 64];
    const int lane = threadIdx.x & 63;
    const int wid  = threadIdx.x >> 6;
    #pragma unroll
    for (int off = 32; off > 0; off >>= 1) v += __shfl_down(v, off, 64);
    if (lane == 0) sm[wid] = v;
    __syncthreads();
    if (wid == 0) {
        v = (lane < TPB / 64) ? sm[lane] : 0.0;
        #pragma unroll
        for (int off = (TPB / 64) / 2; off > 0; off >>= 1) v += __shfl_down(v, off, 64);
    }
    return v;
}

__global__ __launch_bounds__(TPB) void geo_partial(
    const float* __restrict__ a, const float* __restrict__ b,
    double* __restrict__ partial, long long nsamp)
{
    const int lane = threadIdx.x & 63;
    const int wid  = threadIdx.x >> 6;
    const long long gwave  = (long long)blockIdx.x * (TPB / 64) + wid;
    const long long nwaves = (long long)gridDim.x * (TPB / 64);

    // lane -> (group g of 9 lanes, rank r); lane 63 inactive
    const int g = lane / 9;
    const int r = lane - 9 * g;
    const bool active = (lane < 63);
    const int head = (4 * r) / 9;
    int nh = 9 * (head + 1) - 4 * r;       // words of this lane belonging to head sample
    if (nh > 4) nh = 4;
    const bool owner = active && ((r & 1) == 0) && (r < 8);   // r in {0,2,4,6}
    const int k = r >> 1;

    const long long total_f4 = nsamp * 9 / 4;
    const long long n_iters  = (nsamp + 27) / 28;

    const f32x4* a4 = reinterpret_cast<const f32x4*>(a);
    const f32x4* b4 = reinterpret_cast<const f32x4*>(b);

    double acc = 0.0;
    // 4-deep pipeline: iters itb + u*nwaves, u=0..3. Out-of-range its are safe:
    // f4i >= total_f4 -> zeros -> owner guard (s<nsamp) rejects.
    for (long long itb = gwave; itb < n_iters; itb += 4 * nwaves) {
        f32x4 x[4], y[4];
        #pragma unroll
        for (int u = 0; u < 4; ++u) {
            const long long it  = itb + u * nwaves;
            const long long f4i = it * 63 + lane;
            x[u] = (f32x4){0.f, 0.f, 0.f, 0.f};
            y[u] = (f32x4){0.f, 0.f, 0.f, 0.f};
            if (active && f4i < total_f4) {
                x[u] = __builtin_nontemporal_load(a4 + f4i);
                y[u] = __builtin_nontemporal_load(b4 + f4i);
            }
        }
        #pragma unroll
        for (int u = 0; u < 4; ++u) {
            const long long it = itb + u * nwaves;
            const float p0 = x[u].x * y[u].x, p1 = x[u].y * y[u].y;
            const float p2 = x[u].z * y[u].z, p3 = x[u].w * y[u].w;
            const float pre2 = p0 + p1, pre3 = pre2 + p2, pre4 = pre3 + p3;
            const float suf3 = p3, suf2 = p2 + p3, suf1 = p1 + suf2;
            const float pearly = (nh == 1) ? p0 : (nh == 2) ? pre2 : (nh == 3) ? pre3 : pre4;
            const float plate  = (nh == 4) ? pre4 : (nh == 1) ? suf1 : (nh == 2) ? suf2 : suf3;

            const float v1 = __shfl(plate,  lane + 1, 64);
            const float v2 = __shfl(pearly, lane + 2, 64);

            if (owner) {
                const long long s = it * 28 + 4 * g + k;
                if (s < nsamp) {
                    const float dot = plate + v1 + v2;
                    float c = (dot - 1.0f) * 0.5f;
                    c = fminf(fmaxf(c, -1.0f + EPSF), 1.0f - EPSF);
                    acc += (double)acosf(c);
                }
            }
        }
    }

    const double rsum = block_reduce(acc);
    if (threadIdx.x == 0) partial[blockIdx.x] = rsum;
}

__global__ __launch_bounds__(TPB) void geo_final(
    const double* __restrict__ partial, float* __restrict__ out,
    int n, double inv_n)
{
    double acc = 0.0;
    for (int i = threadIdx.x; i < n; i += TPB) acc += partial[i];
    const double r = block_reduce(acc);
    if (threadIdx.x == 0) out[0] = (float)(r * inv_n);
}

extern "C" void kernel_launch(void* const* d_in, const int* in_sizes, int n_in,
                              void* d_out, int out_size, void* d_ws, size_t ws_size,
                              hipStream_t stream) {
    const float* a = (const float*)d_in[0];   // ypred [B,3,3] f32
    const float* b = (const float*)d_in[1];   // ytrue [B,3,3] f32
    float* out = (float*)d_out;               // scalar f32
    const long long nsamp = in_sizes[0] / 9;

    double* partial = (double*)d_ws;          // NBLK doubles; all written every launch

    geo_partial<<<NBLK, TPB, 0, stream>>>(a, b, partial, nsamp);
    geo_final<<<1, TPB, 0, stream>>>(partial, out, NBLK, 1.0 / (double)nsamp);
}